// Round 15
// baseline (6980.877 us; speedup 1.0000x reference)
//
#include <hip/hip_runtime.h>

// ConvGRU: 2-layer GRU, B=32, T=512, D=H=512, fp32 in/out, bf16 MFMA compute.
// Round-21: r20 base (6182 us; MV32 kept, measured == r18) + ONE change:
//   PACKED FLAG LINES (8 flags/line, 64 x 8B = 512B = 8 lines). Old spin
//   gathered 64 SEPARATE lines (4KB) per poll -> worst-of-64 L3 RT (~1us)
//   per poll round and ~19K line-req/us standing L3 load from ~300 polling
//   waves. New poll is one COALESCED 64-lane x 8B load over 8 lines.
//   Stores: 8 writers/line, ~1 write/0.75us/line in lockstep (r17's failure
//   was 64 BYTE-writers on ONE line; r7's dense-flag regression was
//   confounded with decoupling's free-running poll contention -- density
//   alone was never isolated. This is that isolation.)
// Pre-committed: <=5700 -> gather-latency confirmed, keep; 5900-6400 ->
// neutral, declare exchange-latency floor next round; >=6600 -> dense-flag
// store contention real, revert + declare.

#define Bn 32
#define Tn 512
#define Dn 512
#define Hn 512
#define KKn 1024
#define NBLK 64
#define NTHR 384
#define NTHREADS (NBLK * NTHR)
#define RING (Tn + 2)

typedef __bf16 bf16x8 __attribute__((ext_vector_type(8)));
typedef float floatx4 __attribute__((ext_vector_type(4)));

// ---- persistent device state ----
__device__ unsigned short g_h0R[RING][Bn * Hn];   // h0 after t-1 at slot t
__device__ unsigned short g_h1R[RING][Bn * Hn];   // h1 after t'-1 at slot t'
__device__ unsigned short g_hr0R[RING][Bn * Hn];  // h0 (.) r0, slot s
__device__ unsigned short g_hr1R[RING][Bn * Hn];  // h1 (.) r1, slot s
__device__ unsigned short g_Xproj[3][Tn][Bn][Hn]; // bf16 x-projections (u,r,o)
__device__ unsigned short g_Wxb[3][Dn * Hn];      // layer0 x-half weights bf16
__device__ __attribute__((aligned(64))) unsigned long long g_slot[NBLK]; // packed: 8 flags/line

__device__ __forceinline__ bf16x8 ldb8(const unsigned short* p) {
    return *reinterpret_cast<const bf16x8*>(p);
}
__device__ __forceinline__ unsigned short f2b(float f) {
    union { float f; unsigned u; } v; v.f = f;
    unsigned u = v.u;
    return (unsigned short)((u + 0x7fffu + ((u >> 16) & 1u)) >> 16);  // RNE
}
__device__ __forceinline__ float b2fs(unsigned short b) {
    union { unsigned u; float f; } v; v.u = ((unsigned)b) << 16; return v.f;
}
__device__ __forceinline__ unsigned long long ald8(const void* p) {
    return __hip_atomic_load((const unsigned long long*)p, __ATOMIC_RELAXED,
                             __HIP_MEMORY_SCOPE_AGENT);
}
__device__ __forceinline__ void ast8(void* p, unsigned long long v) {
    __hip_atomic_store((unsigned long long*)p, v, __ATOMIC_RELAXED,
                       __HIP_MEMORY_SCOPE_AGENT);
}
__device__ __forceinline__ void ast4u(unsigned* p, unsigned v) {
    __hip_atomic_store(p, v, __ATOMIC_RELAXED, __HIP_MEMORY_SCOPE_AGENT);
}

__device__ __forceinline__ void spin(unsigned long long tgt, int lane) {
    while (true) {
        unsigned long long v = ald8(&g_slot[lane]);   // coalesced 8-line gather
        if (__all(v >= tgt)) break;
        __builtin_amdgcn_s_sleep(1);
    }
}

__device__ __forceinline__ floatx4 mfma(bf16x8 a, bf16x8 b, floatx4 c) {
    return __builtin_amdgcn_mfma_f32_16x16x32_bf16(a, b, c, 0, 0, 0);
}
__device__ __forceinline__ bf16x8 cvt8(floatx4 v0, floatx4 v1) {
    bf16x8 a;
    a[0] = (__bf16)v0[0]; a[1] = (__bf16)v0[1]; a[2] = (__bf16)v0[2]; a[3] = (__bf16)v0[3];
    a[4] = (__bf16)v1[0]; a[5] = (__bf16)v1[1]; a[6] = (__bf16)v1[2]; a[7] = (__bf16)v1[3];
    return a;
}

// 16-frag matvec: issue ALL 16 loads first (static reg arrays), then 16 MFMAs.
#define MV16(P, WOFF, ACC) do {                                          \
    bf16x8 s0_[8], s1_[8];                                               \
    _Pragma("unroll")                                                    \
    for (int i_ = 0; i_ < 8; ++i_) s0_[i_] = ldb8((P) + i_ * 32);        \
    _Pragma("unroll")                                                    \
    for (int i_ = 0; i_ < 8; ++i_) s1_[i_] = ldb8((P) + (8 + i_) * 32);  \
    _Pragma("unroll")                                                    \
    for (int i_ = 0; i_ < 8; ++i_) ACC = mfma(s0_[i_], wreg[(WOFF) + i_], ACC); \
    _Pragma("unroll")                                                    \
    for (int i_ = 0; i_ < 8; ++i_) ACC = mfma(s1_[i_], wreg[(WOFF) + 8 + i_], ACC); \
} while (0)

// 32-frag matvec: issue ALL 32 loads (16 from P0 + 16 from P1), THEN 32 MFMAs.
#define MV32(P0, P1, ACC) do {                                           \
    bf16x8 a0_[8], a1_[8], b0_[8], b1_[8];                               \
    _Pragma("unroll")                                                    \
    for (int i_ = 0; i_ < 8; ++i_) a0_[i_] = ldb8((P0) + i_ * 32);       \
    _Pragma("unroll")                                                    \
    for (int i_ = 0; i_ < 8; ++i_) a1_[i_] = ldb8((P0) + (8 + i_) * 32); \
    _Pragma("unroll")                                                    \
    for (int i_ = 0; i_ < 8; ++i_) b0_[i_] = ldb8((P1) + i_ * 32);       \
    _Pragma("unroll")                                                    \
    for (int i_ = 0; i_ < 8; ++i_) b1_[i_] = ldb8((P1) + (8 + i_) * 32); \
    _Pragma("unroll")                                                    \
    for (int i_ = 0; i_ < 8; ++i_) ACC = mfma(a0_[i_], wreg[i_], ACC);   \
    _Pragma("unroll")                                                    \
    for (int i_ = 0; i_ < 8; ++i_) ACC = mfma(a1_[i_], wreg[8 + i_], ACC); \
    _Pragma("unroll")                                                    \
    for (int i_ = 0; i_ < 8; ++i_) ACC = mfma(b0_[i_], wreg[16 + i_], ACC); \
    _Pragma("unroll")                                                    \
    for (int i_ = 0; i_ < 8; ++i_) ACC = mfma(b1_[i_], wreg[24 + i_], ACC); \
} while (0)

__global__ __launch_bounds__(NTHR, 1) void gru_persist(
    const float* __restrict__ x,
    const float* __restrict__ Wr, const float* __restrict__ br,
    const float* __restrict__ Wu, const float* __restrict__ bu,
    const float* __restrict__ Wo, const float* __restrict__ bo,
    float* __restrict__ out)
{
    const int tid  = threadIdx.x;
    const int lane = tid & 63;
    const int widx = tid >> 6;          // 0..5
    const int gate = widx >> 1;         // 0=u, 1=r, 2=o
    const int hf   = widx & 1;          // row-tile half
    const int rb   = hf * 16;           // row base
    const int quad = lane >> 4;
    const int lo   = lane & 15;
    const int blk  = blockIdx.x;
    const int l    = blk >> 5;          // layer 0..1
    const int n0   = (blk & 31) * 16;   // n-tile

    __shared__ float lds_u[Bn * 16];

    unsigned long long ep = ald8(&g_slot[blk]);

    // ================= phase 0: zero ring slot 0; cvt layer0 x-weights =====
    {
        int gtid = blk * NTHR + tid;
        unsigned* h0z = (unsigned*)&g_h0R[0][0];
        unsigned* h1z = (unsigned*)&g_h1R[0][0];
        for (int i = gtid; i < (Bn * Hn) / 2; i += NTHREADS) {
            h0z[i] = 0u;
            h1z[i] = 0u;
        }
        for (int i = gtid * 4; i < 3 * Dn * Hn; i += NTHREADS * 4) {
            int g = i / (Dn * Hn);
            int rem = i - g * (Dn * Hn);
            int n = rem >> 9, k = rem & 511;
            const float* ws = (g == 0) ? Wu : (g == 1) ? Wr : Wo;
            floatx4 v = *reinterpret_cast<const floatx4*>(ws + (size_t)n * KKn + k);
            ushort4 pk = make_ushort4(f2b(v[0]), f2b(v[1]), f2b(v[2]), f2b(v[3]));
            *reinterpret_cast<ushort4*>(&g_Wxb[0][0] + i) = pk;
        }
    }
    ep++;
    __syncthreads();
    if (tid == 0) { __threadfence(); ast8(&g_slot[blk], ep); }
    spin(ep, lane);
    if (widx == 0) __threadfence();
    __syncthreads();

    // ================= phase 1: Xproj GEMM (layer0 x-projections) ==========
    // 384 wave-jobs: 3 gates x 128 chunks x 128 token-rows (8 mt of 16).
    {
        int gid = blk * 6 + widx;       // 0..383
        int g = gid >> 7;               // gate 0..2
        int chunk = gid & 127;          // 128 token-rows each
        for (int mt = 0; mt < 8; ++mt) {
            int m0 = chunk * 128 + mt * 16;
            int t = m0 >> 5;
            int bh = m0 & 31;           // 0 or 16
            const float* xrow = x + (size_t)(bh + lo) * Tn * Dn + (size_t)t * Dn + quad * 8;
            bf16x8 af[16];
            #pragma unroll
            for (int i = 0; i < 16; ++i) {
                floatx4 v0 = *reinterpret_cast<const floatx4*>(xrow + i * 32);
                floatx4 v1 = *reinterpret_cast<const floatx4*>(xrow + i * 32 + 4);
                af[i] = cvt8(v0, v1);
            }
            for (int nt = 0; nt < 32; ++nt) {
                floatx4 acc = {0.f, 0.f, 0.f, 0.f};
                const unsigned short* wp = &g_Wxb[g][0] + (size_t)(nt * 16 + lo) * Dn + quad * 8;
                #pragma unroll
                for (int i = 0; i < 16; ++i)
                    acc = mfma(af[i], ldb8(wp + i * 32), acc);
                #pragma unroll
                for (int rr = 0; rr < 4; ++rr)
                    g_Xproj[g][t][bh + quad * 4 + rr][nt * 16 + lo] = f2b(acc[rr]);
            }
        }
    }
    ep++;
    __syncthreads();
    if (tid == 0) { __threadfence(); ast8(&g_slot[blk], ep); }
    spin(ep, lane);
    if (widx == 0) __threadfence();
    __syncthreads();

    // ================= register-resident recurrent weights =================
    // All fills fully static-unrolled (r12 fix); all uses static (r18 fix).
    const float* Wsrc = (gate == 0) ? Wu : (gate == 1) ? Wr : Wo;
    const float bias = ((gate == 0) ? bu : (gate == 1) ? br : bo)[l * Hn + n0 + lo];
    bf16x8 wreg[32];
    {
        const int koff = (l == 0) ? Dn : 0;
        const float* wp = Wsrc + (size_t)l * Hn * KKn + (size_t)(n0 + lo) * KKn + koff + quad * 8;
        #pragma unroll
        for (int i = 0; i < 16; ++i) {
            floatx4 v0 = *reinterpret_cast<const floatx4*>(wp + i * 32);
            floatx4 v1 = *reinterpret_cast<const floatx4*>(wp + i * 32 + 4);
            wreg[i] = cvt8(v0, v1);
        }
        if (l == 1) {
            const float* wp2 = wp + Dn;   // K = 512..1023 (h1 half)
            #pragma unroll
            for (int i = 0; i < 16; ++i) {
                floatx4 v0 = *reinterpret_cast<const floatx4*>(wp2 + i * 32);
                floatx4 v1 = *reinterpret_cast<const floatx4*>(wp2 + i * 32 + 4);
                wreg[16 + i] = cvt8(v0, v1);
            }
        } else {
            #pragma unroll
            for (int i = 0; i < 16; ++i)
                wreg[16 + i] = wreg[i];   // static default; unused for l==0
        }
    }

    float hreg0[4] = {0.f, 0.f, 0.f, 0.f};

    // ================= steady wavefront loop =================
    for (int s = 0; s <= Tn; ++s) {
        const bool act = (l == 0) ? (s < Tn) : (s >= 1);

        // ---- A-phase: u-waves (0,1) and r-waves (2,3), one row-tile each --
        if (gate < 2 && act) {
            floatx4 a0 = {0.f, 0.f, 0.f, 0.f};
            if (l == 0) {
                const unsigned short* xp = &g_Xproj[gate][s][0][n0 + lo];
                #pragma unroll
                for (int rr = 0; rr < 4; ++rr)
                    a0[rr] = b2fs(xp[(size_t)(rb + quad * 4 + rr) * Hn]);
                const unsigned short* p0 = g_h0R[s] + (size_t)(rb + lo) * Hn + quad * 8;
                MV16(p0, 0, a0);
            } else {
                const unsigned short* p0 = g_h0R[s]     + (size_t)(rb + lo) * Hn + quad * 8;
                const unsigned short* q0 = g_h1R[s - 1] + (size_t)(rb + lo) * Hn + quad * 8;
                MV32(p0, q0, a0);
            }
            if (gate == 0) {
                // u -> LDS (block-local)
                #pragma unroll
                for (int rr = 0; rr < 4; ++rr) {
                    int r0 = rb + quad * 4 + rr;
                    lds_u[r0 * 16 + lo] = 1.f / (1.f + __expf(-(a0[rr] + bias)));
                }
            } else {
                // r -> hr = h (.) r -> bypass store to ring
                const unsigned short* h = (l == 0) ? g_h0R[s] : g_h1R[s - 1];
                unsigned short* hr = (l == 0) ? g_hr0R[s] : g_hr1R[s];
                #pragma unroll
                for (int rr = 0; rr < 4; ++rr) {
                    int r0 = rb + quad * 4 + rr;
                    float rv = 1.f / (1.f + __expf(-(a0[rr] + bias)));
                    float hv = b2fs(h[(size_t)r0 * Hn + n0 + lo]);
                    unsigned w0 = f2b(hv * rv);
                    unsigned pp0 = (unsigned)__shfl_xor((int)w0, 1);
                    if ((lo & 1) == 0)
                        ast4u((unsigned*)(hr + (size_t)r0 * Hn + n0 + lo), w0 | (pp0 << 16));
                }
            }
        }

        // ---- alpha barrier: arrive ----
        ep++;
        __syncthreads();
        if (tid == 0) ast8(&g_slot[blk], ep);

        // ---- B-waves (4,5): precompute x-part, spin, (h.r)@Wo + update ----
        if (gate == 2) {
            floatx4 a0 = {0.f, 0.f, 0.f, 0.f};
            if (act) {
                if (l == 0) {
                    const unsigned short* xp = &g_Xproj[2][s][0][n0 + lo];
                    #pragma unroll
                    for (int rr = 0; rr < 4; ++rr)
                        a0[rr] = b2fs(xp[(size_t)(rb + quad * 4 + rr) * Hn]);
                } else {
                    const unsigned short* p0 = g_h0R[s] + (size_t)(rb + lo) * Hn + quad * 8;
                    MV16(p0, 0, a0);
                }
            }
            spin(ep, lane);
            if (act) {
                const unsigned short* hr = (l == 0) ? g_hr0R[s] : g_hr1R[s];
                const unsigned short* p0 = hr + (size_t)(rb + lo) * Hn + quad * 8;
                if (l == 0) { MV16(p0, 0, a0); }
                else        { MV16(p0, 16, a0); }
                unsigned short* hpub = (l == 0) ? g_h0R[s + 1] : g_h1R[s];
                bool fin = (l == 0) ? (s == Tn - 1) : (s == Tn);
                #pragma unroll
                for (int rr = 0; rr < 4; ++rr) {
                    int r0 = rb + quad * 4 + rr;
                    float o0 = tanhf(a0[rr] + bias);
                    float u0 = lds_u[r0 * 16 + lo];
                    hreg0[rr] += u0 * (o0 - hreg0[rr]);
                    unsigned w0 = f2b(hreg0[rr]);
                    unsigned pp0 = (unsigned)__shfl_xor((int)w0, 1);
                    if ((lo & 1) == 0)
                        ast4u((unsigned*)(hpub + (size_t)r0 * Hn + n0 + lo), w0 | (pp0 << 16));
                    if (fin) {
                        out[(size_t)l * Bn * Hn + (size_t)r0 * Hn + n0 + lo] = hreg0[rr];
                    }
                }
            }
        }

        // ---- beta barrier: all waves spin ----
        ep++;
        __syncthreads();
        if (tid == 0) ast8(&g_slot[blk], ep);
        spin(ep, lane);
    }
}

extern "C" void kernel_launch(void* const* d_in, const int* in_sizes, int n_in,
                              void* d_out, int out_size, void* d_ws, size_t ws_size,
                              hipStream_t stream) {
    const float* x  = (const float*)d_in[0];
    const float* Wr = (const float*)d_in[1];
    const float* br = (const float*)d_in[2];
    const float* Wu = (const float*)d_in[3];
    const float* bu = (const float*)d_in[4];
    const float* Wo = (const float*)d_in[5];
    const float* bo = (const float*)d_in[6];
    float* out = (float*)d_out;

    gru_persist<<<NBLK, NTHR, 0, stream>>>(x, Wr, br, Wu, bu, Wo, bo, out);
}

// Round 16
// 6227.728 us; speedup vs baseline: 1.1209x; 1.1209x over previous
//
#include <hip/hip_runtime.h>

// ConvGRU: 2-layer GRU, B=32, T=512, D=H=512, fp32 in/out, bf16 MFMA compute.
// Round-22: REVERT to round-20 exactly (verified best 6182 us, absmax
// 0.00439). Round-21's packed flag lines hit the pre-committed failure
// branch (+12%, absmax shifted -> visibility-ordering perturbation).
// Flag-density question closed: 64 lines (1/block) is optimal; 8-line and
// 1-line layouts both regress. All isolable mechanisms now probed; if this
// reproduces ~6180, the session declares the exchange-latency floor:
// 2 cross-XCD sync rounds x 513 steps x ~6us irreducible latency+jitter.

#define Bn 32
#define Tn 512
#define Dn 512
#define Hn 512
#define KKn 1024
#define NBLK 64
#define NTHR 384
#define NTHREADS (NBLK * NTHR)
#define RING (Tn + 2)

typedef __bf16 bf16x8 __attribute__((ext_vector_type(8)));
typedef float floatx4 __attribute__((ext_vector_type(4)));

// ---- persistent device state ----
__device__ unsigned short g_h0R[RING][Bn * Hn];   // h0 after t-1 at slot t
__device__ unsigned short g_h1R[RING][Bn * Hn];   // h1 after t'-1 at slot t'
__device__ unsigned short g_hr0R[RING][Bn * Hn];  // h0 (.) r0, slot s
__device__ unsigned short g_hr1R[RING][Bn * Hn];  // h1 (.) r1, slot s
__device__ unsigned short g_Xproj[3][Tn][Bn][Hn]; // bf16 x-projections (u,r,o)
__device__ unsigned short g_Wxb[3][Dn * Hn];      // layer0 x-half weights bf16
__device__ unsigned long long g_slot[NBLK * 8];   // per-block epoch slots (own line)

__device__ __forceinline__ bf16x8 ldb8(const unsigned short* p) {
    return *reinterpret_cast<const bf16x8*>(p);
}
__device__ __forceinline__ unsigned short f2b(float f) {
    union { float f; unsigned u; } v; v.f = f;
    unsigned u = v.u;
    return (unsigned short)((u + 0x7fffu + ((u >> 16) & 1u)) >> 16);  // RNE
}
__device__ __forceinline__ float b2fs(unsigned short b) {
    union { unsigned u; float f; } v; v.u = ((unsigned)b) << 16; return v.f;
}
__device__ __forceinline__ unsigned long long ald8(const void* p) {
    return __hip_atomic_load((const unsigned long long*)p, __ATOMIC_RELAXED,
                             __HIP_MEMORY_SCOPE_AGENT);
}
__device__ __forceinline__ void ast8(void* p, unsigned long long v) {
    __hip_atomic_store((unsigned long long*)p, v, __ATOMIC_RELAXED,
                       __HIP_MEMORY_SCOPE_AGENT);
}
__device__ __forceinline__ void ast4u(unsigned* p, unsigned v) {
    __hip_atomic_store(p, v, __ATOMIC_RELAXED, __HIP_MEMORY_SCOPE_AGENT);
}

__device__ __forceinline__ void spin(unsigned long long tgt, int lane) {
    while (true) {
        unsigned long long v = ald8(&g_slot[lane * 8]);
        if (__all(v >= tgt)) break;
        __builtin_amdgcn_s_sleep(1);
    }
}

__device__ __forceinline__ floatx4 mfma(bf16x8 a, bf16x8 b, floatx4 c) {
    return __builtin_amdgcn_mfma_f32_16x16x32_bf16(a, b, c, 0, 0, 0);
}
__device__ __forceinline__ bf16x8 cvt8(floatx4 v0, floatx4 v1) {
    bf16x8 a;
    a[0] = (__bf16)v0[0]; a[1] = (__bf16)v0[1]; a[2] = (__bf16)v0[2]; a[3] = (__bf16)v0[3];
    a[4] = (__bf16)v1[0]; a[5] = (__bf16)v1[1]; a[6] = (__bf16)v1[2]; a[7] = (__bf16)v1[3];
    return a;
}

// 16-frag matvec: issue ALL 16 loads first (static reg arrays), then 16 MFMAs.
#define MV16(P, WOFF, ACC) do {                                          \
    bf16x8 s0_[8], s1_[8];                                               \
    _Pragma("unroll")                                                    \
    for (int i_ = 0; i_ < 8; ++i_) s0_[i_] = ldb8((P) + i_ * 32);        \
    _Pragma("unroll")                                                    \
    for (int i_ = 0; i_ < 8; ++i_) s1_[i_] = ldb8((P) + (8 + i_) * 32);  \
    _Pragma("unroll")                                                    \
    for (int i_ = 0; i_ < 8; ++i_) ACC = mfma(s0_[i_], wreg[(WOFF) + i_], ACC); \
    _Pragma("unroll")                                                    \
    for (int i_ = 0; i_ < 8; ++i_) ACC = mfma(s1_[i_], wreg[(WOFF) + 8 + i_], ACC); \
} while (0)

// 32-frag matvec: issue ALL 32 loads (16 from P0 + 16 from P1), THEN 32 MFMAs.
#define MV32(P0, P1, ACC) do {                                           \
    bf16x8 a0_[8], a1_[8], b0_[8], b1_[8];                               \
    _Pragma("unroll")                                                    \
    for (int i_ = 0; i_ < 8; ++i_) a0_[i_] = ldb8((P0) + i_ * 32);       \
    _Pragma("unroll")                                                    \
    for (int i_ = 0; i_ < 8; ++i_) a1_[i_] = ldb8((P0) + (8 + i_) * 32); \
    _Pragma("unroll")                                                    \
    for (int i_ = 0; i_ < 8; ++i_) b0_[i_] = ldb8((P1) + i_ * 32);       \
    _Pragma("unroll")                                                    \
    for (int i_ = 0; i_ < 8; ++i_) b1_[i_] = ldb8((P1) + (8 + i_) * 32); \
    _Pragma("unroll")                                                    \
    for (int i_ = 0; i_ < 8; ++i_) ACC = mfma(a0_[i_], wreg[i_], ACC);   \
    _Pragma("unroll")                                                    \
    for (int i_ = 0; i_ < 8; ++i_) ACC = mfma(a1_[i_], wreg[8 + i_], ACC); \
    _Pragma("unroll")                                                    \
    for (int i_ = 0; i_ < 8; ++i_) ACC = mfma(b0_[i_], wreg[16 + i_], ACC); \
    _Pragma("unroll")                                                    \
    for (int i_ = 0; i_ < 8; ++i_) ACC = mfma(b1_[i_], wreg[24 + i_], ACC); \
} while (0)

__global__ __launch_bounds__(NTHR, 1) void gru_persist(
    const float* __restrict__ x,
    const float* __restrict__ Wr, const float* __restrict__ br,
    const float* __restrict__ Wu, const float* __restrict__ bu,
    const float* __restrict__ Wo, const float* __restrict__ bo,
    float* __restrict__ out)
{
    const int tid  = threadIdx.x;
    const int lane = tid & 63;
    const int widx = tid >> 6;          // 0..5
    const int gate = widx >> 1;         // 0=u, 1=r, 2=o
    const int hf   = widx & 1;          // row-tile half
    const int rb   = hf * 16;           // row base
    const int quad = lane >> 4;
    const int lo   = lane & 15;
    const int blk  = blockIdx.x;
    const int l    = blk >> 5;          // layer 0..1
    const int n0   = (blk & 31) * 16;   // n-tile

    __shared__ float lds_u[Bn * 16];

    unsigned long long ep = ald8(&g_slot[blk * 8]);

    // ================= phase 0: zero ring slot 0; cvt layer0 x-weights =====
    {
        int gtid = blk * NTHR + tid;
        unsigned* h0z = (unsigned*)&g_h0R[0][0];
        unsigned* h1z = (unsigned*)&g_h1R[0][0];
        for (int i = gtid; i < (Bn * Hn) / 2; i += NTHREADS) {
            h0z[i] = 0u;
            h1z[i] = 0u;
        }
        for (int i = gtid * 4; i < 3 * Dn * Hn; i += NTHREADS * 4) {
            int g = i / (Dn * Hn);
            int rem = i - g * (Dn * Hn);
            int n = rem >> 9, k = rem & 511;
            const float* ws = (g == 0) ? Wu : (g == 1) ? Wr : Wo;
            floatx4 v = *reinterpret_cast<const floatx4*>(ws + (size_t)n * KKn + k);
            ushort4 pk = make_ushort4(f2b(v[0]), f2b(v[1]), f2b(v[2]), f2b(v[3]));
            *reinterpret_cast<ushort4*>(&g_Wxb[0][0] + i) = pk;
        }
    }
    ep++;
    __syncthreads();
    if (tid == 0) { __threadfence(); ast8(&g_slot[blk * 8], ep); }
    spin(ep, lane);
    if (widx == 0) __threadfence();
    __syncthreads();

    // ================= phase 1: Xproj GEMM (layer0 x-projections) ==========
    // 384 wave-jobs: 3 gates x 128 chunks x 128 token-rows (8 mt of 16).
    {
        int gid = blk * 6 + widx;       // 0..383
        int g = gid >> 7;               // gate 0..2
        int chunk = gid & 127;          // 128 token-rows each
        for (int mt = 0; mt < 8; ++mt) {
            int m0 = chunk * 128 + mt * 16;
            int t = m0 >> 5;
            int bh = m0 & 31;           // 0 or 16
            const float* xrow = x + (size_t)(bh + lo) * Tn * Dn + (size_t)t * Dn + quad * 8;
            bf16x8 af[16];
            #pragma unroll
            for (int i = 0; i < 16; ++i) {
                floatx4 v0 = *reinterpret_cast<const floatx4*>(xrow + i * 32);
                floatx4 v1 = *reinterpret_cast<const floatx4*>(xrow + i * 32 + 4);
                af[i] = cvt8(v0, v1);
            }
            for (int nt = 0; nt < 32; ++nt) {
                floatx4 acc = {0.f, 0.f, 0.f, 0.f};
                const unsigned short* wp = &g_Wxb[g][0] + (size_t)(nt * 16 + lo) * Dn + quad * 8;
                #pragma unroll
                for (int i = 0; i < 16; ++i)
                    acc = mfma(af[i], ldb8(wp + i * 32), acc);
                #pragma unroll
                for (int rr = 0; rr < 4; ++rr)
                    g_Xproj[g][t][bh + quad * 4 + rr][nt * 16 + lo] = f2b(acc[rr]);
            }
        }
    }
    ep++;
    __syncthreads();
    if (tid == 0) { __threadfence(); ast8(&g_slot[blk * 8], ep); }
    spin(ep, lane);
    if (widx == 0) __threadfence();
    __syncthreads();

    // ================= register-resident recurrent weights =================
    // All fills fully static-unrolled (r12 fix); all uses static (r18 fix).
    const float* Wsrc = (gate == 0) ? Wu : (gate == 1) ? Wr : Wo;
    const float bias = ((gate == 0) ? bu : (gate == 1) ? br : bo)[l * Hn + n0 + lo];
    bf16x8 wreg[32];
    {
        const int koff = (l == 0) ? Dn : 0;
        const float* wp = Wsrc + (size_t)l * Hn * KKn + (size_t)(n0 + lo) * KKn + koff + quad * 8;
        #pragma unroll
        for (int i = 0; i < 16; ++i) {
            floatx4 v0 = *reinterpret_cast<const floatx4*>(wp + i * 32);
            floatx4 v1 = *reinterpret_cast<const floatx4*>(wp + i * 32 + 4);
            wreg[i] = cvt8(v0, v1);
        }
        if (l == 1) {
            const float* wp2 = wp + Dn;   // K = 512..1023 (h1 half)
            #pragma unroll
            for (int i = 0; i < 16; ++i) {
                floatx4 v0 = *reinterpret_cast<const floatx4*>(wp2 + i * 32);
                floatx4 v1 = *reinterpret_cast<const floatx4*>(wp2 + i * 32 + 4);
                wreg[16 + i] = cvt8(v0, v1);
            }
        } else {
            #pragma unroll
            for (int i = 0; i < 16; ++i)
                wreg[16 + i] = wreg[i];   // static default; unused for l==0
        }
    }

    float hreg0[4] = {0.f, 0.f, 0.f, 0.f};

    // ================= steady wavefront loop =================
    for (int s = 0; s <= Tn; ++s) {
        const bool act = (l == 0) ? (s < Tn) : (s >= 1);

        // ---- A-phase: u-waves (0,1) and r-waves (2,3), one row-tile each --
        if (gate < 2 && act) {
            floatx4 a0 = {0.f, 0.f, 0.f, 0.f};
            if (l == 0) {
                const unsigned short* xp = &g_Xproj[gate][s][0][n0 + lo];
                #pragma unroll
                for (int rr = 0; rr < 4; ++rr)
                    a0[rr] = b2fs(xp[(size_t)(rb + quad * 4 + rr) * Hn]);
                const unsigned short* p0 = g_h0R[s] + (size_t)(rb + lo) * Hn + quad * 8;
                MV16(p0, 0, a0);
            } else {
                const unsigned short* p0 = g_h0R[s]     + (size_t)(rb + lo) * Hn + quad * 8;
                const unsigned short* q0 = g_h1R[s - 1] + (size_t)(rb + lo) * Hn + quad * 8;
                MV32(p0, q0, a0);
            }
            if (gate == 0) {
                // u -> LDS (block-local)
                #pragma unroll
                for (int rr = 0; rr < 4; ++rr) {
                    int r0 = rb + quad * 4 + rr;
                    lds_u[r0 * 16 + lo] = 1.f / (1.f + __expf(-(a0[rr] + bias)));
                }
            } else {
                // r -> hr = h (.) r -> bypass store to ring
                const unsigned short* h = (l == 0) ? g_h0R[s] : g_h1R[s - 1];
                unsigned short* hr = (l == 0) ? g_hr0R[s] : g_hr1R[s];
                #pragma unroll
                for (int rr = 0; rr < 4; ++rr) {
                    int r0 = rb + quad * 4 + rr;
                    float rv = 1.f / (1.f + __expf(-(a0[rr] + bias)));
                    float hv = b2fs(h[(size_t)r0 * Hn + n0 + lo]);
                    unsigned w0 = f2b(hv * rv);
                    unsigned pp0 = (unsigned)__shfl_xor((int)w0, 1);
                    if ((lo & 1) == 0)
                        ast4u((unsigned*)(hr + (size_t)r0 * Hn + n0 + lo), w0 | (pp0 << 16));
                }
            }
        }

        // ---- alpha barrier: arrive ----
        ep++;
        __syncthreads();
        if (tid == 0) ast8(&g_slot[blk * 8], ep);

        // ---- B-waves (4,5): precompute x-part, spin, (h.r)@Wo + update ----
        if (gate == 2) {
            floatx4 a0 = {0.f, 0.f, 0.f, 0.f};
            if (act) {
                if (l == 0) {
                    const unsigned short* xp = &g_Xproj[2][s][0][n0 + lo];
                    #pragma unroll
                    for (int rr = 0; rr < 4; ++rr)
                        a0[rr] = b2fs(xp[(size_t)(rb + quad * 4 + rr) * Hn]);
                } else {
                    const unsigned short* p0 = g_h0R[s] + (size_t)(rb + lo) * Hn + quad * 8;
                    MV16(p0, 0, a0);
                }
            }
            spin(ep, lane);
            if (act) {
                const unsigned short* hr = (l == 0) ? g_hr0R[s] : g_hr1R[s];
                const unsigned short* p0 = hr + (size_t)(rb + lo) * Hn + quad * 8;
                if (l == 0) { MV16(p0, 0, a0); }
                else        { MV16(p0, 16, a0); }
                unsigned short* hpub = (l == 0) ? g_h0R[s + 1] : g_h1R[s];
                bool fin = (l == 0) ? (s == Tn - 1) : (s == Tn);
                #pragma unroll
                for (int rr = 0; rr < 4; ++rr) {
                    int r0 = rb + quad * 4 + rr;
                    float o0 = tanhf(a0[rr] + bias);
                    float u0 = lds_u[r0 * 16 + lo];
                    hreg0[rr] += u0 * (o0 - hreg0[rr]);
                    unsigned w0 = f2b(hreg0[rr]);
                    unsigned pp0 = (unsigned)__shfl_xor((int)w0, 1);
                    if ((lo & 1) == 0)
                        ast4u((unsigned*)(hpub + (size_t)r0 * Hn + n0 + lo), w0 | (pp0 << 16));
                    if (fin) {
                        out[(size_t)l * Bn * Hn + (size_t)r0 * Hn + n0 + lo] = hreg0[rr];
                    }
                }
            }
        }

        // ---- beta barrier: all waves spin ----
        ep++;
        __syncthreads();
        if (tid == 0) ast8(&g_slot[blk * 8], ep);
        spin(ep, lane);
    }
}

extern "C" void kernel_launch(void* const* d_in, const int* in_sizes, int n_in,
                              void* d_out, int out_size, void* d_ws, size_t ws_size,
                              hipStream_t stream) {
    const float* x  = (const float*)d_in[0];
    const float* Wr = (const float*)d_in[1];
    const float* br = (const float*)d_in[2];
    const float* Wu = (const float*)d_in[3];
    const float* bu = (const float*)d_in[4];
    const float* Wo = (const float*)d_in[5];
    const float* bo = (const float*)d_in[6];
    float* out = (float*)d_out;

    gru_persist<<<NBLK, NTHR, 0, stream>>>(x, Wr, br, Wu, bu, Wo, bo, out);
}